// Round 1
// baseline (326.862 us; speedup 1.0000x reference)
//
#include <hip/hip_runtime.h>

#define SEQ 512
#define NB  512
#define NT  96

// One block per batch element. Thread j (0..95) owns tag-column j.
// Forward recursion in shifted-exp domain:
//   lv[j] = alpha[j] - C ;  e[k] = exp(lv[k] - d), d = lv[0] (broadcast)
//   v[j]  = sum_k e[k] * expT[k][j]   (expT[:,j] held in 96 VGPRs)
//   lv'[j] = log(v[j]) + em[i][j] ;  C += d
__launch_bounds__(96)
__global__ void crf_fwd_kernel(const float* __restrict__ logits,
                               const int*   __restrict__ tags,
                               const int*   __restrict__ mask,
                               const float* __restrict__ trans,
                               const float* __restrict__ startt,
                               const float* __restrict__ endt,
                               float* __restrict__ out)
{
    const int b = blockIdx.x;
    const int j = threadIdx.x;              // 0..95
    const float* em = logits + (size_t)b * SEQ * NT;   // em[i*NT + t]

    __shared__ __align__(16) float e_buf[NT];
    __shared__ float d_lds;
    __shared__ float red[NT];
    __shared__ float num_red[NT];
    __shared__ int   tg_s[SEQ];
    __shared__ int   mk_s[SEQ];

    // stage tags/mask rows for this batch
    for (int i = j; i < SEQ; i += NT) {
        tg_s[i] = tags[(size_t)b * SEQ + i];
        mk_s[i] = mask[(size_t)b * SEQ + i];
    }

    // expT column j into registers (coalesced across lanes per k)
    float col[NT];
#pragma unroll
    for (int k = 0; k < NT; ++k) {
        col[k] = __expf(trans[k * NT + j]);
    }

    // init: alpha0 = start + em[0]
    float lv = startt[j] + em[j];
    float C  = 0.f;
    if (j == 0) d_lds = lv;

    // software-pipelined emission loads (2 steps ahead)
    float emA = em[1 * NT + j];             // for step 1
    float emB = em[2 * NT + j];             // for step 2
    __syncthreads();

    for (int i = 1; i < SEQ; ++i) {
        const float d = d_lds;              // shift (prev iter's lv[0])
        const bool active = (mk_s[i] != 0); // uniform across block
        const float e = __expf(lv - d);     // e[0] == 1 exactly
        e_buf[j] = e;
        // prefetch emission row for step i+2
        const float emC = (i + 2 < SEQ) ? em[(i + 2) * NT + j] : 0.f;
        __syncthreads();                    // barrier B: e_buf ready

        const float4* e4 = (const float4*)e_buf;
        float a0 = 0.f, a1 = 0.f, a2 = 0.f, a3 = 0.f;
#pragma unroll
        for (int k4 = 0; k4 < NT / 4; ++k4) {
            const float4 ev = e4[k4];       // broadcast read, conflict-free
            a0 = fmaf(ev.x, col[4 * k4 + 0], a0);
            a1 = fmaf(ev.y, col[4 * k4 + 1], a1);
            a2 = fmaf(ev.z, col[4 * k4 + 2], a2);
            a3 = fmaf(ev.w, col[4 * k4 + 3], a3);
        }
        const float v   = (a0 + a1) + (a2 + a3);
        const float lvn = __logf(v) + emA;
        if (active) { lv = lvn; C += d; }
        if (j == 0) d_lds = lv;             // safe: readers read pre-barrier-B
        emA = emB; emB = emC;
        __syncthreads();                    // barrier A: protect e_buf + d_lds
    }

    // ---- denominator: C + logsumexp_j(lv[j] + end[j]) ----
    red[j] = lv + endt[j];

    // ---- numerator partials (strided over steps) ----
    float part = 0.f;
    for (int i = 1 + j; i < SEQ; i += NT) {
        if (mk_s[i]) {
            const int tp = tg_s[i - 1], tc = tg_s[i];
            part += trans[tp * NT + tc] + em[i * NT + tc];
        }
    }
    num_red[j] = part;
    __syncthreads();

    if (j == 0) {
        // denominator reduce (exact logsumexp)
        float m = red[0];
        for (int k = 1; k < NT; ++k) m = fmaxf(m, red[k]);
        float s = 0.f;
        for (int k = 0; k < NT; ++k) s += __expf(red[k] - m);
        const float denom = C + m + __logf(s);

        // numerator
        float num = startt[tg_s[0]] + em[tg_s[0]];
        for (int k = 0; k < NT; ++k) num += num_red[k];
        int cnt = 0;
        for (int i = 0; i < SEQ; ++i) cnt += mk_s[i];
        num += endt[tg_s[cnt - 1]];

        atomicAdd(out, num - denom);
    }
}

extern "C" void kernel_launch(void* const* d_in, const int* in_sizes, int n_in,
                              void* d_out, int out_size, void* d_ws, size_t ws_size,
                              hipStream_t stream)
{
    const float* logits = (const float*)d_in[0];
    const int*   tags   = (const int*)  d_in[1];
    const int*   mask   = (const int*)  d_in[2];
    const float* trans  = (const float*)d_in[3];
    const float* startt = (const float*)d_in[4];
    const float* endt   = (const float*)d_in[5];
    float* out = (float*)d_out;

    hipMemsetAsync(out, 0, out_size * sizeof(float), stream);
    crf_fwd_kernel<<<NB, NT, 0, stream>>>(logits, tags, mask, trans,
                                          startt, endt, out);
}